// Round 20
// baseline (37.377 us; speedup 1.0000x reference)
//
#include <hip/hip_runtime.h>
#include <math.h>

#define BB 2
#define NN 1024
#define HH 4
#define F_IN 128
#define HID 32
#define TJ 64
#define NT 16
#define CT 4           // tiles per j-quarter

#define LOG2E 1.44269504f

typedef unsigned long long u64;
typedef unsigned int u32;
typedef _Float16 f16;
typedef _Float16 h2    __attribute__((ext_vector_type(2)));
typedef _Float16 f16x4 __attribute__((ext_vector_type(4)));
typedef _Float16 f16x8 __attribute__((ext_vector_type(8)));
typedef float f32x4 __attribute__((ext_vector_type(4)));

// ---- workspace layout (bytes) ----
#define WS_XH  0           // f16 x  [bh][n][k=32]   = 524288
#define WS_D6  524288      // f32 d6 [bh][n]         = 32768
#define WS_XT  557056      // f16 X^T[bh][k=32][n]   = 524288

#if __has_builtin(__builtin_amdgcn_fdot2)
#define FDOT2(a, b, c) __builtin_amdgcn_fdot2((a), (b), (c), false)
#else
static __device__ __forceinline__ float FDOT2(h2 a, h2 b, float c) {
    return fmaf((float)a[0], (float)b[0], fmaf((float)a[1], (float)b[1], c));
}
#endif

template <typename D, typename S>
static __device__ __forceinline__ D bcast(S s) { return __builtin_bit_cast(D, s); }

// ---------------- Kernel 1: proj (x=feat@W) -> xh(f16 [n][k]) + xt(f16 [k][n]) + d6
// (R15-R19-verbatim)
__global__ __launch_bounds__(128) void gat_proj_kernel(const float* __restrict__ feat,
        const float* __restrict__ W, const float* __restrict__ Wa,
        f16* __restrict__ xh, f16* __restrict__ xt, float* __restrict__ d6) {
    const int RPB = 4;
    int blk = blockIdx.x;              // 0 .. BB*NN/4-1
    int b  = blk / (NN / RPB);
    int n0 = (blk % (NN / RPB)) * RPB;
    int t  = threadIdx.x;              // 0..127 -> output column h*32+k

    __shared__ float fs[RPB][F_IN];
#pragma unroll
    for (int e = 0; e < RPB; ++e) {
        int idx = e * 128 + t;
        int r = idx >> 7, f = idx & 127;
        fs[r][f] = feat[((size_t)(b*NN + n0 + r))*F_IN + f];
    }
    __syncthreads();

    float acc[RPB];
#pragma unroll
    for (int r = 0; r < RPB; ++r) acc[r] = 0.f;
    for (int f = 0; f < F_IN; ++f) {
        float w = W[f*(HH*HID) + t];
#pragma unroll
        for (int r = 0; r < RPB; ++r) acc[r] = fmaf(fs[r][f], w, acc[r]);
    }

    int h = t >> 5, k = t & 31;
    int bh = b*HH + h;
#pragma unroll
    for (int r = 0; r < RPB; ++r)
        xh[((size_t)bh*NN + n0 + r)*HID + k] = (f16)acc[r];
    {
        f16x4 hv;
#pragma unroll
        for (int r = 0; r < RPB; ++r) hv[r] = (f16)acc[r];
        *(f16x4*)(xt + ((size_t)bh*HID + k)*NN + n0) = hv;
    }
    float w_t = Wa[t];
#pragma unroll
    for (int r = 0; r < RPB; ++r) {
        float p = acc[r] * w_t;
#pragma unroll
        for (int off = 16; off >= 1; off >>= 1) p += __shfl_xor(p, off, 32);
        if (k == 0) d6[(size_t)bh*NN + n0 + r] = 0.6f * LOG2E * p;
    }
}

__device__ __forceinline__ u32 srfl(u32 v) { return __builtin_amdgcn_readfirstlane(v); }

// ---------------- Kernel 2: FUSED score + MFMA aggregation, 1024 thr (16 waves).
// Block = (bh, 16-row i-tile); 512 blocks -> 2 blocks/CU, 8 waves/SIMD (VGPR<=64).
// Phase 1 (R17 core): wave w -> row-quad q4=w&3, j-quarter hf=w>>2 (4 tiles);
// barrier-free; P -> LDS [16][1032]; quarter lsum partials -> lsp4[4][16].
// Phase 2: 16 waves x 2 jt MFMA K-slices (R14-validated frags); scr[16] reduce.
__global__ __launch_bounds__(1024, 8) void gat_fused_kernel(const f16* __restrict__ xh,
                                                            const float* __restrict__ d6,
                                                            const int* __restrict__ adj,
                                                            const float* __restrict__ Wa,
                                                            const f16* __restrict__ xt,
                                                            float* __restrict__ out) {
    const int tid = threadIdx.x;
    const int w = __builtin_amdgcn_readfirstlane(tid >> 6);   // wave 0..15
    const int l = tid & 63;
    const int blk = blockIdx.x;                // 0..511
    const int bh = blk & 7;                    // XCD pin
    const int i0 = (blk >> 3) << 4;            // 16 rows per block
    const int h = bh & 3, b = bh >> 2;
    const int q4 = w & 3, hf = w >> 2;         // row-quad, j-quarter
    const int ib = i0 + 4*q4;                  // wave's first row

    const u32* xhu = (const u32*)(xh + (size_t)bh*NN*HID);    // 16 u32 per row
    const float* dbh = d6 + (size_t)bh*NN;

    __shared__ __align__(16) f16 Pl[16][1032]; // 33.0 KB (pad 8)
    __shared__ float scr[16][64][9];           // 36.9 KB (pad 9)
    __shared__ float lsp4[4][16];              // quarter lsum partials

    // ---- prologue (R17-verbatim): packed wa + 4 rows of xi -> SGPRs
    u32 wa2[16];
    {
        const float* wap = Wa + h*HID;
#pragma unroll
        for (int q = 0; q < 16; ++q) {
            h2 hw;
            hw[0] = (f16)((0.4f*LOG2E) * wap[2*q]);
            hw[1] = (f16)((0.4f*LOG2E) * wap[2*q+1]);
            wa2[q] = srfl(bcast<u32>(hw));
        }
    }
    u32 xi2[4][16];
    float ci[4];
#pragma unroll
    for (int r = 0; r < 4; ++r) {
        const u32* xr = xhu + (size_t)(ib + r)*16;
#pragma unroll
        for (int q = 0; q < 16; ++q) xi2[r][q] = srfl(xr[q]);
        ci[r] = __uint_as_float(srfl(__float_as_uint(dbh[ib + r]))) - 8.0f;
    }

    const int* adj0 = adj + ((size_t)b*NN + ib + 0)*NN;
    const int* adj1 = adj + ((size_t)b*NN + ib + 1)*NN;
    const int* adj2 = adj + ((size_t)b*NN + ib + 2)*NN;
    const int* adj3 = adj + ((size_t)b*NN + ib + 3)*NN;

    float ls0 = 0.f, ls1 = 0.f, ls2 = 0.f, ls3 = 0.f;

    // ---- phase 1: scores over this wave's j-quarter (R17 core)
    for (int tt = 0; tt < CT; ++tt) {
        const int j = (hf*CT + tt)*TJ + l;
        u64 m0 = __ballot(adj0[j] > 0);
        u64 m1 = __ballot(adj1[j] > 0);
        u64 m2 = __ballot(adj2[j] > 0);
        u64 m3 = __ballot(adj3[j] > 0);
        float dj = dbh[j];

        const u32* xjp = xhu + (size_t)j*16;
        uint4 xa = *(const uint4*)(xjp);
        uint4 xb = *(const uint4*)(xjp + 4);
        uint4 xc = *(const uint4*)(xjp + 8);
        uint4 xd = *(const uint4*)(xjp + 12);
        u32 xj[16] = {xa.x, xa.y, xa.z, xa.w, xb.x, xb.y, xb.z, xb.w,
                      xc.x, xc.y, xc.z, xc.w, xd.x, xd.y, xd.z, xd.w};

        float s0 = 0.f, s1 = 0.f, s2 = 0.f, s3 = 0.f;
#pragma unroll
        for (int q = 0; q < 16; ++q) {
            h2 xjh = bcast<h2>(xj[q]);
            h2 wq  = bcast<h2>(wa2[q]);
            h2 v; u32 a;
            v = bcast<h2>(xi2[0][q]) + xjh; a = bcast<u32>(v) & 0x7fff7fffu;
            s0 = FDOT2(bcast<h2>(a), wq, s0);
            v = bcast<h2>(xi2[1][q]) + xjh; a = bcast<u32>(v) & 0x7fff7fffu;
            s1 = FDOT2(bcast<h2>(a), wq, s1);
            v = bcast<h2>(xi2[2][q]) + xjh; a = bcast<u32>(v) & 0x7fff7fffu;
            s2 = FDOT2(bcast<h2>(a), wq, s2);
            v = bcast<h2>(xi2[3][q]) + xjh; a = bcast<u32>(v) & 0x7fff7fffu;
            s3 = FDOT2(bcast<h2>(a), wq, s3);
        }
        float p0 = exp2f(ci[0] + dj + s0);
        float p1 = exp2f(ci[1] + dj + s1);
        float p2 = exp2f(ci[2] + dj + s2);
        float p3 = exp2f(ci[3] + dj + s3);
        asm("v_cndmask_b32 %0, 0, %1, %2" : "=v"(p0) : "v"(p0), "s"(m0));
        asm("v_cndmask_b32 %0, 0, %1, %2" : "=v"(p1) : "v"(p1), "s"(m1));
        asm("v_cndmask_b32 %0, 0, %1, %2" : "=v"(p2) : "v"(p2), "s"(m2));
        asm("v_cndmask_b32 %0, 0, %1, %2" : "=v"(p3) : "v"(p3), "s"(m3));
        ls0 += p0; ls1 += p1; ls2 += p2; ls3 += p3;
        Pl[4*q4 + 0][j] = (f16)p0;
        Pl[4*q4 + 1][j] = (f16)p1;
        Pl[4*q4 + 2][j] = (f16)p2;
        Pl[4*q4 + 3][j] = (f16)p3;
    }

    // quarter denominator partials -> LDS
#pragma unroll
    for (int off = 32; off >= 1; off >>= 1) {
        ls0 += __shfl_xor(ls0, off, 64);
        ls1 += __shfl_xor(ls1, off, 64);
        ls2 += __shfl_xor(ls2, off, 64);
        ls3 += __shfl_xor(ls3, off, 64);
    }
    if (l == 0) {
        lsp4[hf][4*q4 + 0] = ls0;
        lsp4[hf][4*q4 + 1] = ls1;
        lsp4[hf][4*q4 + 2] = ls2;
        lsp4[hf][4*q4 + 3] = ls3;
    }
    __syncthreads();

    // ---- phase 2: MFMA agg. wave w -> jt = 2w..2w+1 (K slice), R14-validated frags.
    const f16* xtb = xt + (size_t)bh * HID * NN;
    const int lrow = l & 15, lslot = (l >> 4) << 3;

    f32x4 acc0 = {0.f, 0.f, 0.f, 0.f};
    f32x4 acc1 = {0.f, 0.f, 0.f, 0.f};
#pragma unroll
    for (int q = 0; q < 2; ++q) {
        const int joff = (w*2 + q)*32 + lslot;
        f16x8 af = *(const f16x8*)&Pl[lrow][joff];
        f16x8 b0 = *(const f16x8*)(xtb + (size_t)lrow*NN + joff);
        f16x8 b1 = *(const f16x8*)(xtb + (size_t)(16 + lrow)*NN + joff);
        acc0 = __builtin_amdgcn_mfma_f32_16x16x32_f16(af, b0, acc0, 0, 0, 0);
        acc1 = __builtin_amdgcn_mfma_f32_16x16x32_f16(af, b1, acc1, 0, 0, 0);
    }

    // partial C -> padded LDS
#pragma unroll
    for (int e = 0; e < 4; ++e) {
        scr[w][l][e]     = acc0[e];
        scr[w][l][4 + e] = acc1[e];
    }
    __syncthreads();

    // reduce 16 wave-partials; thread (w<8, l) handles C-slot e=w.
    // C/D mapping (HW-verified): e<4 -> acc0[e]: row=i0+(l>>4)*4+e, col=lrow;
    // e>=4 -> acc1[e-4]: row=i0+(l>>4)*4+(e-4), col=16+lrow.
    if (w < 8) {
        float s = 0.f;
#pragma unroll
        for (int ww = 0; ww < 16; ++ww) s += scr[ww][l][w];
        const int r = w & 3;
        const int col = ((w >= 4) ? 16 : 0) + lrow;
        const int rloc = ((l >> 4) << 2) + r;
        const int row = i0 + rloc;
        float inv = 1.0f / (lsp4[0][rloc] + lsp4[1][rloc] + lsp4[2][rloc] + lsp4[3][rloc]);
        out[((size_t)(b*NN + row))*(HH*HID) + h*HID + col] = s * inv;
    }
}

extern "C" void kernel_launch(void* const* d_in, const int* in_sizes, int n_in,
                              void* d_out, int out_size, void* d_ws, size_t ws_size,
                              hipStream_t stream) {
    const float* node_feat = (const float*)d_in[0];
    const int*   adj_mtx   = (const int*)d_in[1];
    const float* W         = (const float*)d_in[2];
    const float* Wa        = (const float*)d_in[3];
    float* out = (float*)d_out;

    char* ws = (char*)d_ws;
    f16*   xh_ws = (f16*)(ws + WS_XH);
    float* d6_ws = (float*)(ws + WS_D6);
    f16*   xt_ws = (f16*)(ws + WS_XT);

    hipLaunchKernelGGL(gat_proj_kernel, dim3(BB*NN/4), dim3(128), 0, stream,
                       node_feat, W, Wa, xh_ws, xt_ws, d6_ws);
    hipLaunchKernelGGL(gat_fused_kernel, dim3(8 * (NN/16)), dim3(1024), 0, stream,
                       xh_ws, d6_ws, adj_mtx, Wa, xt_ws, out);
}

// Round 21
// 35.833 us; speedup vs baseline: 1.0431x; 1.0431x over previous
//
#include <hip/hip_runtime.h>
#include <math.h>

#define BB 2
#define NN 1024
#define HH 4
#define F_IN 128
#define HID 32
#define TJ 64
#define NT 16
#define CT 8           // tiles per j-half

#define LOG2E 1.44269504f

typedef unsigned long long u64;
typedef unsigned int u32;
typedef _Float16 f16;
typedef _Float16 h2    __attribute__((ext_vector_type(2)));
typedef _Float16 f16x4 __attribute__((ext_vector_type(4)));
typedef _Float16 f16x8 __attribute__((ext_vector_type(8)));
typedef float f32x4 __attribute__((ext_vector_type(4)));

// ---- workspace layout (bytes) ----
#define WS_XH  0           // f16 x  [bh][n][k=32]   = 524288
#define WS_D6  524288      // f32 d6 [bh][n]         = 32768
#define WS_XT  557056      // f16 X^T[bh][k=32][n]   = 524288

#if __has_builtin(__builtin_amdgcn_fdot2)
#define FDOT2(a, b, c) __builtin_amdgcn_fdot2((a), (b), (c), false)
#else
static __device__ __forceinline__ float FDOT2(h2 a, h2 b, float c) {
    return fmaf((float)a[0], (float)b[0], fmaf((float)a[1], (float)b[1], c));
}
#endif

template <typename D, typename S>
static __device__ __forceinline__ D bcast(S s) { return __builtin_bit_cast(D, s); }

// ---------------- Kernel 1: proj (x=feat@W) -> xh(f16 [n][k]) + xt(f16 [k][n]) + d6
__global__ __launch_bounds__(128) void gat_proj_kernel(const float* __restrict__ feat,
        const float* __restrict__ W, const float* __restrict__ Wa,
        f16* __restrict__ xh, f16* __restrict__ xt, float* __restrict__ d6) {
    const int RPB = 4;
    int blk = blockIdx.x;              // 0 .. BB*NN/4-1
    int b  = blk / (NN / RPB);
    int n0 = (blk % (NN / RPB)) * RPB;
    int t  = threadIdx.x;              // 0..127 -> output column h*32+k

    __shared__ float fs[RPB][F_IN];
#pragma unroll
    for (int e = 0; e < RPB; ++e) {
        int idx = e * 128 + t;
        int r = idx >> 7, f = idx & 127;
        fs[r][f] = feat[((size_t)(b*NN + n0 + r))*F_IN + f];
    }
    __syncthreads();

    float acc[RPB];
#pragma unroll
    for (int r = 0; r < RPB; ++r) acc[r] = 0.f;
    for (int f = 0; f < F_IN; ++f) {
        float w = W[f*(HH*HID) + t];
#pragma unroll
        for (int r = 0; r < RPB; ++r) acc[r] = fmaf(fs[r][f], w, acc[r]);
    }

    int h = t >> 5, k = t & 31;
    int bh = b*HH + h;
#pragma unroll
    for (int r = 0; r < RPB; ++r)
        xh[((size_t)bh*NN + n0 + r)*HID + k] = (f16)acc[r];
    {
        f16x4 hv;
#pragma unroll
        for (int r = 0; r < RPB; ++r) hv[r] = (f16)acc[r];
        *(f16x4*)(xt + ((size_t)bh*HID + k)*NN + n0) = hv;
    }
    float w_t = Wa[t];
#pragma unroll
    for (int r = 0; r < RPB; ++r) {
        float p = acc[r] * w_t;
#pragma unroll
        for (int off = 16; off >= 1; off >>= 1) p += __shfl_xor(p, off, 32);
        if (k == 0) d6[(size_t)bh*NN + n0 + r] = 0.6f * LOG2E * p;
    }
}

__device__ __forceinline__ u32 srfl(u32 v) { return __builtin_amdgcn_readfirstlane(v); }

// ---------------- Kernel 2: FUSED score + MFMA aggregation (R17 = measured best).
// 512 thr (8 waves); block = (bh, 16-row i-tile).
// Phase 1: wave w -> row-quad q=w&3 (rows 4q..4q+3), j-half hf=w>>2 (8 tiles).
// Barrier-free; packed-f16 score core (pk_add + abs-mask + fdot2); P -> LDS
// [16][1032] (pad 8); half-range lsum partials -> lsp2[2][16].
// Phase 2: 8 waves x 4 jt MFMA from LDS-P (A) + global xt (B); scr-reduce;
// divide by combined lsum; write out.
__global__ __launch_bounds__(512) void gat_fused_kernel(const f16* __restrict__ xh,
                                                        const float* __restrict__ d6,
                                                        const int* __restrict__ adj,
                                                        const float* __restrict__ Wa,
                                                        const f16* __restrict__ xt,
                                                        float* __restrict__ out) {
    const int tid = threadIdx.x;
    const int w = __builtin_amdgcn_readfirstlane(tid >> 6);   // wave 0..7
    const int l = tid & 63;
    const int blk = blockIdx.x;                // 0..511
    const int bh = blk & 7;                    // XCD pin
    const int i0 = (blk >> 3) << 4;            // 16 rows per block
    const int h = bh & 3, b = bh >> 2;
    const int q4 = w & 3, hf = w >> 2;         // row-quad, j-half
    const int ib = i0 + 4*q4;                  // wave's first row

    const u32* xhu = (const u32*)(xh + (size_t)bh*NN*HID);    // 16 u32 per row
    const float* dbh = d6 + (size_t)bh*NN;

    __shared__ __align__(16) f16 Pl[16][1032]; // 33.0 KB (pad 8)
    __shared__ float scr[8][64][9];            // 18.4 KB (pad 9)
    __shared__ float lsp2[2][16];              // half-range lsum partials

    // ---- prologue: packed wa + 4 rows of xi -> SGPRs
    u32 wa2[16];
    {
        const float* wap = Wa + h*HID;
#pragma unroll
        for (int q = 0; q < 16; ++q) {
            h2 hw;
            hw[0] = (f16)((0.4f*LOG2E) * wap[2*q]);
            hw[1] = (f16)((0.4f*LOG2E) * wap[2*q+1]);
            wa2[q] = srfl(bcast<u32>(hw));
        }
    }
    u32 xi2[4][16];
    float ci[4];
#pragma unroll
    for (int r = 0; r < 4; ++r) {
        const u32* xr = xhu + (size_t)(ib + r)*16;
#pragma unroll
        for (int q = 0; q < 16; ++q) xi2[r][q] = srfl(xr[q]);
        ci[r] = __uint_as_float(srfl(__float_as_uint(dbh[ib + r]))) - 8.0f;
    }

    const int* adj0 = adj + ((size_t)b*NN + ib + 0)*NN;
    const int* adj1 = adj + ((size_t)b*NN + ib + 1)*NN;
    const int* adj2 = adj + ((size_t)b*NN + ib + 2)*NN;
    const int* adj3 = adj + ((size_t)b*NN + ib + 3)*NN;

    float ls0 = 0.f, ls1 = 0.f, ls2 = 0.f, ls3 = 0.f;

    // ---- phase 1: scores over this wave's j-half
    for (int tt = 0; tt < CT; ++tt) {
        const int j = (hf*CT + tt)*TJ + l;
        u64 m0 = __ballot(adj0[j] > 0);
        u64 m1 = __ballot(adj1[j] > 0);
        u64 m2 = __ballot(adj2[j] > 0);
        u64 m3 = __ballot(adj3[j] > 0);
        float dj = dbh[j];

        const u32* xjp = xhu + (size_t)j*16;
        uint4 xa = *(const uint4*)(xjp);
        uint4 xb = *(const uint4*)(xjp + 4);
        uint4 xc = *(const uint4*)(xjp + 8);
        uint4 xd = *(const uint4*)(xjp + 12);
        u32 xj[16] = {xa.x, xa.y, xa.z, xa.w, xb.x, xb.y, xb.z, xb.w,
                      xc.x, xc.y, xc.z, xc.w, xd.x, xd.y, xd.z, xd.w};

        float s0 = 0.f, s1 = 0.f, s2 = 0.f, s3 = 0.f;
#pragma unroll
        for (int q = 0; q < 16; ++q) {
            h2 xjh = bcast<h2>(xj[q]);
            h2 wq  = bcast<h2>(wa2[q]);
            h2 v; u32 a;
            v = bcast<h2>(xi2[0][q]) + xjh; a = bcast<u32>(v) & 0x7fff7fffu;
            s0 = FDOT2(bcast<h2>(a), wq, s0);
            v = bcast<h2>(xi2[1][q]) + xjh; a = bcast<u32>(v) & 0x7fff7fffu;
            s1 = FDOT2(bcast<h2>(a), wq, s1);
            v = bcast<h2>(xi2[2][q]) + xjh; a = bcast<u32>(v) & 0x7fff7fffu;
            s2 = FDOT2(bcast<h2>(a), wq, s2);
            v = bcast<h2>(xi2[3][q]) + xjh; a = bcast<u32>(v) & 0x7fff7fffu;
            s3 = FDOT2(bcast<h2>(a), wq, s3);
        }
        float p0 = exp2f(ci[0] + dj + s0);
        float p1 = exp2f(ci[1] + dj + s1);
        float p2 = exp2f(ci[2] + dj + s2);
        float p3 = exp2f(ci[3] + dj + s3);
        asm("v_cndmask_b32 %0, 0, %1, %2" : "=v"(p0) : "v"(p0), "s"(m0));
        asm("v_cndmask_b32 %0, 0, %1, %2" : "=v"(p1) : "v"(p1), "s"(m1));
        asm("v_cndmask_b32 %0, 0, %1, %2" : "=v"(p2) : "v"(p2), "s"(m2));
        asm("v_cndmask_b32 %0, 0, %1, %2" : "=v"(p3) : "v"(p3), "s"(m3));
        ls0 += p0; ls1 += p1; ls2 += p2; ls3 += p3;
        Pl[4*q4 + 0][j] = (f16)p0;
        Pl[4*q4 + 1][j] = (f16)p1;
        Pl[4*q4 + 2][j] = (f16)p2;
        Pl[4*q4 + 3][j] = (f16)p3;
    }

    // half-range denominator partials -> LDS
#pragma unroll
    for (int off = 32; off >= 1; off >>= 1) {
        ls0 += __shfl_xor(ls0, off, 64);
        ls1 += __shfl_xor(ls1, off, 64);
        ls2 += __shfl_xor(ls2, off, 64);
        ls3 += __shfl_xor(ls3, off, 64);
    }
    if (l == 0) {
        lsp2[hf][4*q4 + 0] = ls0;
        lsp2[hf][4*q4 + 1] = ls1;
        lsp2[hf][4*q4 + 2] = ls2;
        lsp2[hf][4*q4 + 3] = ls3;
    }
    __syncthreads();

    // ---- phase 2: MFMA agg. wave w -> jt = 4w..4w+3 (K slice).
    const f16* xtb = xt + (size_t)bh * HID * NN;
    const int lrow = l & 15, lslot = (l >> 4) << 3;

    f32x4 acc0 = {0.f, 0.f, 0.f, 0.f};
    f32x4 acc1 = {0.f, 0.f, 0.f, 0.f};
#pragma unroll
    for (int q = 0; q < 4; ++q) {
        const int joff = (w*4 + q)*32 + lslot;
        f16x8 af = *(const f16x8*)&Pl[lrow][joff];
        f16x8 b0 = *(const f16x8*)(xtb + (size_t)lrow*NN + joff);
        f16x8 b1 = *(const f16x8*)(xtb + (size_t)(16 + lrow)*NN + joff);
        acc0 = __builtin_amdgcn_mfma_f32_16x16x32_f16(af, b0, acc0, 0, 0, 0);
        acc1 = __builtin_amdgcn_mfma_f32_16x16x32_f16(af, b1, acc1, 0, 0, 0);
    }

    // partial C -> padded LDS
#pragma unroll
    for (int e = 0; e < 4; ++e) {
        scr[w][l][e]     = acc0[e];
        scr[w][l][4 + e] = acc1[e];
    }
    __syncthreads();

    // reduce 8 wave-partials; thread (w,l) handles C-slot e=w.
    // C/D mapping (HW-verified): e<4 -> acc0[e]: row=i0+(l>>4)*4+e, col=lrow;
    // e>=4 -> acc1[e-4]: row=i0+(l>>4)*4+(e-4), col=16+lrow.
    {
        float s = 0.f;
#pragma unroll
        for (int ww = 0; ww < 8; ++ww) s += scr[ww][l][w];
        const int r = w & 3;
        const int col = ((w >= 4) ? 16 : 0) + lrow;
        const int rloc = ((l >> 4) << 2) + r;
        const int row = i0 + rloc;
        float inv = 1.0f / (lsp2[0][rloc] + lsp2[1][rloc]);
        out[((size_t)(b*NN + row))*(HH*HID) + h*HID + col] = s * inv;
    }
}

extern "C" void kernel_launch(void* const* d_in, const int* in_sizes, int n_in,
                              void* d_out, int out_size, void* d_ws, size_t ws_size,
                              hipStream_t stream) {
    const float* node_feat = (const float*)d_in[0];
    const int*   adj_mtx   = (const int*)d_in[1];
    const float* W         = (const float*)d_in[2];
    const float* Wa        = (const float*)d_in[3];
    float* out = (float*)d_out;

    char* ws = (char*)d_ws;
    f16*   xh_ws = (f16*)(ws + WS_XH);
    float* d6_ws = (float*)(ws + WS_D6);
    f16*   xt_ws = (f16*)(ws + WS_XT);

    hipLaunchKernelGGL(gat_proj_kernel, dim3(BB*NN/4), dim3(128), 0, stream,
                       node_feat, W, Wa, xh_ws, xt_ws, d6_ws);
    hipLaunchKernelGGL(gat_fused_kernel, dim3(8 * (NN/16)), dim3(512), 0, stream,
                       xh_ws, d6_ws, adj_mtx, Wa, xt_ws, out);
}